// Round 16
// baseline (155.172 us; speedup 1.0000x reference)
//
#include <hip/hip_runtime.h>
#include <cstdint>
#include <cstddef>

using f16   = _Float16;
using half4 = __attribute__((ext_vector_type(4))) _Float16;
using half8 = __attribute__((ext_vector_type(8))) _Float16;
using f32x4 = __attribute__((ext_vector_type(4))) float;
using ull   = unsigned long long;

#define DINL __device__ __forceinline__

// global -> LDS async, 16B per lane. LDS dest wave-uniform base + lane*16.
DINL void gload_lds16(const void* gptr, void* lptr) {
  __builtin_amdgcn_global_load_lds(
      reinterpret_cast<const __attribute__((address_space(1))) uint32_t*>(
          reinterpret_cast<uintptr_t>(gptr)),
      reinterpret_cast<__attribute__((address_space(3))) uint32_t*>(
          reinterpret_cast<uintptr_t>(lptr)),
      16, 0, 0);
}

DINL unsigned pkh(float a, float b) {
  unsigned short ha = __builtin_bit_cast(unsigned short, (f16)a);
  unsigned short hb = __builtin_bit_cast(unsigned short, (f16)b);
  return (unsigned)ha | ((unsigned)hb << 16);
}

struct U4 { unsigned x, y, z, w; };

// x -> 16B A-row: [B0..B5 uniform cubic B-spline, silu(x), 0] as 8 f16.
// Funnel-shift placement; validated rounds 5-15 (absmax 0.03125).
DINL U4 expand_pack(float x) {
  float xs = (x + 3.0f) * 1.5f;
  float mf = floorf(xs);
  int   m  = (int)mf;
  float u = xs - mf, u2 = u * u, u3 = u2 * u, um = 1.0f - u;
  float p3 = u3 * (1.0f / 6.0f);
  float p2 = (1.0f + 3.0f * (u + u2 - u3)) * (1.0f / 6.0f);
  float p1 = (4.0f - 6.0f * u2 + 3.0f * u3) * (1.0f / 6.0f);
  float p0 = um * um * um * (1.0f / 6.0f);
  ull P = (ull)pkh(p0, p1) | ((ull)pkh(p2, p3) << 32);
  if ((unsigned)m > 8u) P = 0;
  int s    = m * 16 - 48;
  int sneg = min(63, max(0, -s));
  int spos = min(63, max(0, s));
  int shi2 = min(63, max(0, s - 64));
  ull rlo = (s < 0) ? (P >> sneg) : ((s < 64) ? (P << spos) : 0ull);
  ull rhi = (s < 0) ? 0ull
                    : ((s < 64) ? ((P >> (63 - spos)) >> 1) : (P << shi2));
  float sil = x / (1.0f + __expf(-x));
  U4 r;
  r.x = (unsigned)rlo;
  r.y = (unsigned)(rlo >> 32);
  r.z = (unsigned)rhi;
  r.w = pkh(sil, 0.0f);
  return r;
}

// Weight prep, PRE-SWIZZLED (rule 21): dim slot stored at (d&7)^(n&7) so a
// linear global_load_lds yields the swizzled LDS tile. Validated rounds 2-15.
__global__ __launch_bounds__(256)
void prep_w_kernel(const float* __restrict__ coef, const float* __restrict__ ssp,
                   const float* __restrict__ sb, f16* __restrict__ Wt,
                   int Din, int Dout) {
  int idx = blockIdx.x * 256 + threadIdx.x;
  if (idx >= Din * Dout) return;
  int n = idx / Din;
  int d = idx - n * Din;
  float s = ssp[(size_t)d * Dout + n];
  const float* c = coef + ((size_t)d * Dout + n) * 6;
  half8 wv;
#pragma unroll
  for (int b = 0; b < 6; ++b) wv[b] = (f16)(c[b] * s);
  wv[6] = (f16)sb[(size_t)d * Dout + n];
  wv[7] = (f16)0.0f;
  int dp = (d & ~7) | ((d & 7) ^ (n & 7));
  *reinterpret_cast<half8*>(Wt + ((size_t)n * Din + dp) * 8) = wv;
}

// ---------------------------------------------------------------------------
// Fused KAN GEMM v16 — v11 tile (BM=64 x BN=256, 8 waves of 32x64) with B
// SINGLE-buffered: LDS 80KB -> 48KB -> 3 blocks/CU (the one variable that
// moved perf across 15 rounds: per-block-step cost is ~4200cyc regardless of
// schedule; m97's 912 TF = same step econ at 3 blocks/CU vs our 2).
// 2-barrier/step m97 schedule: compute(s) -> bar -> stageB(s+1)+expand A(s+1)
// -> bar. Register-pressure-minimized (r14 spill lesson): single-pointer B
// staging, 2 live x floats, 1-elem/thread A staging. launch_bounds(512,6):
// VGPR cap 85 (v11 measured 64 with identical acc+addressing).
// ---------------------------------------------------------------------------
template <bool BIAS, typename TIN, typename TOUT>
__global__ __launch_bounds__(512, 6)
void kan_gemm(const TIN* __restrict__ X, int ldx,
              const f16* __restrict__ Wt, int ldw,
              const float* __restrict__ nscale, const float* __restrict__ nbias,
              int N, TOUT* __restrict__ Out, int nsteps) {
  __shared__ alignas(16) f16 A0[64 * 64];      //  8 KB
  __shared__ alignas(16) f16 A1[64 * 64];      //  8 KB
  __shared__ alignas(16) f16 BB[256 * 64];     // 32 KB (single buffer)

  const int tid  = threadIdx.x;
  const int w    = tid >> 6;
  const int lane = tid & 63;
  const int l15  = lane & 15, l7 = lane & 7, hi = lane >> 4;
  const int wm   = w >> 2, wn = w & 3;         // wave grid 2 x 4
  const int m0   = blockIdx.y * 64;
  const int n0   = blockIdx.x * 256;
  const int dim0 = blockIdx.z * (nsteps * 8);  // split-K dim offset
  TOUT* outz = Out + (size_t)blockIdx.z * ((size_t)gridDim.y * 64) * N;

  // A: 1 element/thread/step (64 rows x 8 dims = 512); asrc is DIM-indexed.
  const int ar = tid >> 3, ad = tid & 7;
  const TIN* asrc = X + (size_t)(m0 + ar) * ldx + dim0 + ad;
  const int aoff = ar * 64 + 8 * (ad ^ (ar & 7));

  // B: 4 x 16B chunks/thread via ONE pointer: chunk c = tid + q*512 ->
  // row (tid>>3) + q*64, slot tid&7; dest = c*16B (linear, rule 21).
  const f16* wsrc = Wt + (size_t)(n0 + (tid >> 3)) * ldw + (size_t)dim0 * 8 + (tid & 7) * 8;

  f32x4 acc[2][4] = {};

  auto stageB = [&](int k0) {
#pragma unroll
    for (int q = 0; q < 4; ++q)
      gload_lds16(wsrc + (size_t)q * 64 * ldw + k0, BB + tid * 8 + q * 4096);
  };

  auto compute = [&](const f16* bA) {
    __builtin_amdgcn_s_setprio(1);
#pragma unroll
    for (int kk = 0; kk < 2; ++kk) {
      const int sl = kk * 4 + hi;
      half8 av[2], bv[4];
#pragma unroll
      for (int i = 0; i < 2; ++i)
        av[i] = *reinterpret_cast<const half8*>(
            bA + (wm * 32 + i * 16 + l15) * 64 + 8 * (sl ^ l7));
#pragma unroll
      for (int j = 0; j < 4; ++j)
        bv[j] = *reinterpret_cast<const half8*>(
            BB + (wn * 64 + j * 16 + l15) * 64 + 8 * (sl ^ l7));
#pragma unroll
      for (int i = 0; i < 2; ++i)
#pragma unroll
        for (int j = 0; j < 4; ++j)
          acc[i][j] = __builtin_amdgcn_mfma_f32_16x16x32_f16(av[i], bv[j], acc[i][j], 0, 0, 0);
    }
    __builtin_amdgcn_s_setprio(0);
  };

  auto writeA = [&](f16* buf, U4 e) {
    *reinterpret_cast<U4*>(buf + aoff) = e;
  };

  // ---- prologue: A(0)->A0, B(0)->BB; xn = x(1) in flight ----
  {
    float xa = (float)asrc[0];
    stageB(0);
    writeA(A0, expand_pack(xa));
  }
  float xn = (float)asrc[8];                   // x(1)
  __syncthreads();                             // drains B(0) + x loads

  // ---- steady state: pair loop, static A names, single BB ----
  const int npairs = (nsteps - 2) >> 1;        // covers steps 0..nsteps-3
  for (int p = 0; p < npairs; ++p) {
    // even step s=2p: compute A0/B(s); then stage B(s+1) || expand x(s+1)
    compute(A0);
    __syncthreads();                           // all BB reads done
    stageB((2 * p + 1) * 64);
    float xa2 = (float)asrc[(2 * p + 2) * 8];  // x(s+2)
    writeA(A1, expand_pack(xn));
    __syncthreads();                           // B(s+1) + A(s+1) visible
    // odd step s=2p+1: compute A1/B(s+1); stage B(s+2) || expand x(s+2)
    compute(A1);
    __syncthreads();
    stageB((2 * p + 2) * 64);
    xn = (float)asrc[(2 * p + 3) * 8];         // x(s+3)
    writeA(A0, expand_pack(xa2));
    __syncthreads();
  }

  // ---- tail: step nsteps-2 (A0), then nsteps-1 (A1) ----
  compute(A0);
  __syncthreads();
  stageB((nsteps - 1) * 64);
  writeA(A1, expand_pack(xn));
  __syncthreads();
  compute(A1);

  // ---- epilogue: Out = ns*acc (+ nb) ----
#pragma unroll
  for (int j = 0; j < 4; ++j) {
    int col   = n0 + wn * 64 + j * 16 + l15;
    float nsv = nscale[col];
    float nbv = BIAS ? nbias[col] : 0.0f;
#pragma unroll
    for (int i = 0; i < 2; ++i) {
      int rb = m0 + wm * 32 + i * 16 + hi * 4;
#pragma unroll
      for (int r = 0; r < 4; ++r)
        outz[(size_t)(rb + r) * N + col] = (TOUT)(nsv * acc[i][j][r] + nbv);
    }
  }
}

// ---------------------------------------------------------------------------
// f16 partial0 + f16 partial1 + node_bias2 + residual -> LN(256) -> exact GELU
// ---------------------------------------------------------------------------
__global__ __launch_bounds__(256)
void ln_gelu_kernel(const f16* __restrict__ P0, const f16* __restrict__ P1,
                    const float* __restrict__ X,  const float* __restrict__ nb2,
                    const float* __restrict__ gamma, const float* __restrict__ beta,
                    float* __restrict__ out, int rows) {
  int row  = blockIdx.x * 4 + (threadIdx.x >> 6);
  int lane = threadIdx.x & 63;
  if (row >= rows) return;
  const half4  a4 = *reinterpret_cast<const half4*>(P0 + (size_t)row * 256 + lane * 4);
  const half4  b4 = *reinterpret_cast<const half4*>(P1 + (size_t)row * 256 + lane * 4);
  const float4 xr = *reinterpret_cast<const float4*>(X  + (size_t)row * 256 + lane * 4);
  const float4 nb = *reinterpret_cast<const float4*>(nb2 + lane * 4);
  const float4 g  = *reinterpret_cast<const float4*>(gamma + lane * 4);
  const float4 be = *reinterpret_cast<const float4*>(beta + lane * 4);
  float h[4];
#pragma unroll
  for (int j = 0; j < 4; ++j)
    h[j] = (float)a4[j] + (float)b4[j] + (&nb.x)[j] + (&xr.x)[j];
  float s = h[0] + h[1] + h[2] + h[3];
#pragma unroll
  for (int o = 32; o >= 1; o >>= 1) s += __shfl_xor(s, o);
  float mu = s * (1.0f / 256.0f);
  float vs = 0.f;
#pragma unroll
  for (int j = 0; j < 4; ++j) { float d = h[j] - mu; vs += d * d; }
#pragma unroll
  for (int o = 32; o >= 1; o >>= 1) vs += __shfl_xor(vs, o);
  float inv = rsqrtf(vs * (1.0f / 256.0f) + 1e-5f);
  float o4[4];
#pragma unroll
  for (int j = 0; j < 4; ++j) {
    float v = (h[j] - mu) * inv * (&g.x)[j] + (&be.x)[j];
    o4[j] = 0.5f * v * (1.0f + erff(v * 0.70710678118654752f));
  }
  *reinterpret_cast<float4*>(out + (size_t)row * 256 + lane * 4) =
      make_float4(o4[0], o4[1], o4[2], o4[3]);
}

// ---------------------------------------------------------------------------
extern "C" void kernel_launch(void* const* d_in, const int* in_sizes, int n_in,
                              void* d_out, int out_size, void* d_ws, size_t ws_size,
                              hipStream_t stream) {
  (void)in_sizes; (void)n_in; (void)out_size; (void)ws_size;
  const float* x     = (const float*)d_in[0];
  const float* coef1 = (const float*)d_in[2];
  const float* sb1   = (const float*)d_in[3];
  const float* ssp1  = (const float*)d_in[4];
  const float* ns1   = (const float*)d_in[5];
  const float* nb1   = (const float*)d_in[6];
  const float* coef2 = (const float*)d_in[8];
  const float* sb2   = (const float*)d_in[9];
  const float* ssp2  = (const float*)d_in[10];
  const float* ns2   = (const float*)d_in[11];
  const float* nb2   = (const float*)d_in[12];
  const float* lgam  = (const float*)d_in[13];
  const float* lbet  = (const float*)d_in[14];
  float* out = (float*)d_out;

  const int Ntok = 16 * 1024;
  const int D0 = 256, D1 = 512, D2 = 256;

  // ws: h1 [Ntok,512] f16 | part [2][Ntok,256] f16 | Wt1 2MB | Wt2 2MB
  char* ws    = (char*)d_ws;
  f16*  h1    = (f16*)ws;
  size_t off  = (size_t)Ntok * D1 * sizeof(f16);
  f16*  part  = (f16*)(ws + off);
  off += (size_t)2 * Ntok * D2 * sizeof(f16);
  f16* Wt1 = (f16*)(ws + off);
  off += (size_t)D1 * D0 * 8 * sizeof(f16);
  f16* Wt2 = (f16*)(ws + off);

  prep_w_kernel<<<(D0 * D1 + 255) / 256, 256, 0, stream>>>(coef1, ssp1, sb1, Wt1, D0, D1);
  prep_w_kernel<<<(D1 * D2 + 255) / 256, 256, 0, stream>>>(coef2, ssp2, sb2, Wt2, D1, D2);

  // layer 1: [16384 x 2048] x [512 x 2048]^T -> h1 (f16). 512 blocks, 3/CU.
  kan_gemm<true, float, f16><<<dim3(D1 / 256, Ntok / 64, 1), 512, 0, stream>>>(
      x, D0, Wt1, D0 * 8, ns1, nb1, D1, h1, D0 / 8);

  // layer 2: full-width N=256, split-K=2 -> 512 blocks; f16 partials ns2*acc.
  kan_gemm<false, f16, f16><<<dim3(D2 / 256, Ntok / 64, 2), 512, 0, stream>>>(
      h1, D1, Wt2, D1 * 8, ns2, nullptr, D2, part, D1 / 16);

  // reduce partials + bias + residual + LN + GELU
  ln_gelu_kernel<<<Ntok / 4, 256, 0, stream>>>(
      part, part + (size_t)Ntok * D2, x, nb2, lgam, lbet, out, Ntok);
}

// Round 17
// 131.066 us; speedup vs baseline: 1.1839x; 1.1839x over previous
//
#include <hip/hip_runtime.h>
#include <cstdint>
#include <cstddef>

using f16   = _Float16;
using half4 = __attribute__((ext_vector_type(4))) _Float16;
using half8 = __attribute__((ext_vector_type(8))) _Float16;
using f32x4 = __attribute__((ext_vector_type(4))) float;
using ull   = unsigned long long;

#define DINL __device__ __forceinline__

// global -> LDS async, 16B per lane. LDS dest wave-uniform base + lane*16.
DINL void gload_lds16(const void* gptr, void* lptr) {
  __builtin_amdgcn_global_load_lds(
      reinterpret_cast<const __attribute__((address_space(1))) uint32_t*>(
          reinterpret_cast<uintptr_t>(gptr)),
      reinterpret_cast<__attribute__((address_space(3))) uint32_t*>(
          reinterpret_cast<uintptr_t>(lptr)),
      16, 0, 0);
}

DINL unsigned pkh(float a, float b) {
  unsigned short ha = __builtin_bit_cast(unsigned short, (f16)a);
  unsigned short hb = __builtin_bit_cast(unsigned short, (f16)b);
  return (unsigned)ha | ((unsigned)hb << 16);
}

struct U4 { unsigned x, y, z, w; };

// x -> 16B A-row: [B0..B5 uniform cubic B-spline, silu(x), 0] as 8 f16.
// Funnel-shift placement; validated rounds 5-16 (absmax 0.03125).
DINL U4 expand_pack(float x) {
  float xs = (x + 3.0f) * 1.5f;
  float mf = floorf(xs);
  int   m  = (int)mf;
  float u = xs - mf, u2 = u * u, u3 = u2 * u, um = 1.0f - u;
  float p3 = u3 * (1.0f / 6.0f);
  float p2 = (1.0f + 3.0f * (u + u2 - u3)) * (1.0f / 6.0f);
  float p1 = (4.0f - 6.0f * u2 + 3.0f * u3) * (1.0f / 6.0f);
  float p0 = um * um * um * (1.0f / 6.0f);
  ull P = (ull)pkh(p0, p1) | ((ull)pkh(p2, p3) << 32);
  if ((unsigned)m > 8u) P = 0;
  int s    = m * 16 - 48;
  int sneg = min(63, max(0, -s));
  int spos = min(63, max(0, s));
  int shi2 = min(63, max(0, s - 64));
  ull rlo = (s < 0) ? (P >> sneg) : ((s < 64) ? (P << spos) : 0ull);
  ull rhi = (s < 0) ? 0ull
                    : ((s < 64) ? ((P >> (63 - spos)) >> 1) : (P << shi2));
  float sil = x / (1.0f + __expf(-x));
  U4 r;
  r.x = (unsigned)rlo;
  r.y = (unsigned)(rlo >> 32);
  r.z = (unsigned)rhi;
  r.w = pkh(sil, 0.0f);
  return r;
}

// Weight prep, PRE-SWIZZLED (rule 21): dim slot stored at (d&7)^(n&7) so a
// linear global_load_lds yields the swizzled LDS tile. Validated rounds 2-16.
__global__ __launch_bounds__(256)
void prep_w_kernel(const float* __restrict__ coef, const float* __restrict__ ssp,
                   const float* __restrict__ sb, f16* __restrict__ Wt,
                   int Din, int Dout) {
  int idx = blockIdx.x * 256 + threadIdx.x;
  if (idx >= Din * Dout) return;
  int n = idx / Din;
  int d = idx - n * Din;
  float s = ssp[(size_t)d * Dout + n];
  const float* c = coef + ((size_t)d * Dout + n) * 6;
  half8 wv;
#pragma unroll
  for (int b = 0; b < 6; ++b) wv[b] = (f16)(c[b] * s);
  wv[6] = (f16)sb[(size_t)d * Dout + n];
  wv[7] = (f16)0.0f;
  int dp = (d & ~7) | ((d & 7) ^ (n & 7));
  *reinterpret_cast<half8*>(Wt + ((size_t)n * Din + dp) * 8) = wv;
}

// ---------------------------------------------------------------------------
// Fused KAN GEMM v17 — m97's proven shape on the fused problem:
// 256 threads (4 waves), wave tile 64x64 (32 MFMA/wave-step, v15 compute),
// SINGLE A (8KB) + SINGLE B (32KB) = 40KB LDS, 2-barrier/step schedule
// (r16's, race-free). Residency from the GRID: split-K (blockIdx.z) makes
// 1024 blocks per GEMM -> 3 blocks/CU (launch_bounds(256,3): VGPR cap 170,
// no spill). NSRC=2 sums two f16 input partials during A staging.
// nbias applied only on z==0 (partials sum to ns*acc + nb).
// ---------------------------------------------------------------------------
template <bool BIAS, int NSRC, typename TIN, typename TOUT>
__global__ __launch_bounds__(256, 3)
void kan_gemm(const TIN* __restrict__ X0, const TIN* __restrict__ X1, int ldx,
              const f16* __restrict__ Wt, int ldw,
              const float* __restrict__ nscale, const float* __restrict__ nbias,
              int N, TOUT* __restrict__ Out, int nsteps) {
  __shared__ alignas(16) f16 AA[64 * 64];      //  8 KB (single)
  __shared__ alignas(16) f16 BB[256 * 64];     // 32 KB (single)

  const int tid  = threadIdx.x;
  const int w    = tid >> 6;                   // 4 waves, tile 64x64 each
  const int lane = tid & 63;
  const int l15  = lane & 15, l7 = lane & 7, hi = lane >> 4;
  const int m0   = blockIdx.y * 64;
  const int n0   = blockIdx.x * 256;
  const int dim0 = blockIdx.z * (nsteps * 8);  // split-K dim offset
  TOUT* outz = Out + (size_t)blockIdx.z * ((size_t)gridDim.y * 64) * N;

  // A staging: 2 elems/thread/step (rows ar, ar+32; dim ad). DIM-indexed ptrs.
  const int ar = tid >> 3, ad = tid & 7;
  const TIN* a0 = X0 + (size_t)(m0 + ar) * ldx + dim0 + ad;
  const TIN* a1 = a0 + (size_t)32 * ldx;       // (ar+32)&7 == ar&7
  const TIN* b0 = nullptr;
  const TIN* b1 = nullptr;
  if constexpr (NSRC == 2) {
    b0 = X1 + (size_t)(m0 + ar) * ldx + dim0 + ad;
    b1 = b0 + (size_t)32 * ldx;
  }
  const int aoff0 = ar * 64 + 8 * (ad ^ (ar & 7));
  const int aoff1 = aoff0 + 32 * 64;

  auto loadx = [&](int doff, float& u, float& v) {
    u = (float)a0[doff];
    v = (float)a1[doff];
    if constexpr (NSRC == 2) {
      u += (float)b0[doff];
      v += (float)b1[doff];
    }
  };

  // B staging: 8 x 16B chunks/thread (2048 chunks): chunk c = tid + q*256 ->
  // row (tid>>3)+q*32, slot tid&7; dest linear c*16B (rule 21).
  const f16* wsrc = Wt + (size_t)(n0 + (tid >> 3)) * ldw + (size_t)dim0 * 8 + (tid & 7) * 8;

  f32x4 acc[4][4] = {};

  auto stageB = [&](int k0) {
#pragma unroll
    for (int q = 0; q < 8; ++q)
      gload_lds16(wsrc + (size_t)q * 32 * ldw + k0, BB + tid * 8 + q * 2048);
  };

  auto compute = [&]() {
    __builtin_amdgcn_s_setprio(1);
#pragma unroll
    for (int kk = 0; kk < 2; ++kk) {
      const int sl = kk * 4 + hi;
      half8 av[4], bv[4];
#pragma unroll
      for (int i = 0; i < 4; ++i)
        av[i] = *reinterpret_cast<const half8*>(
            AA + (i * 16 + l15) * 64 + 8 * (sl ^ l7));
#pragma unroll
      for (int j = 0; j < 4; ++j)
        bv[j] = *reinterpret_cast<const half8*>(
            BB + (w * 64 + j * 16 + l15) * 64 + 8 * (sl ^ l7));
#pragma unroll
      for (int i = 0; i < 4; ++i)
#pragma unroll
        for (int j = 0; j < 4; ++j)
          acc[i][j] = __builtin_amdgcn_mfma_f32_16x16x32_f16(av[i], bv[j], acc[i][j], 0, 0, 0);
    }
    __builtin_amdgcn_s_setprio(0);
  };

  // ---- prologue: tile 0 staged; x(1) in flight ----
  {
    float xu, xv;
    loadx(0, xu, xv);
    stageB(0);
    float yu0, yv0;
    loadx(8, yu0, yv0);                        // x(1), rides to first phase-3
    U4 e0 = expand_pack(xu), e1 = expand_pack(xv);
    *reinterpret_cast<U4*>(AA + aoff0) = e0;
    *reinterpret_cast<U4*>(AA + aoff1) = e1;
    __syncthreads();                           // drains stage + x loads

    float yu = yu0, yv = yv0;
    for (int s = 0; s < nsteps - 1; ++s) {
      compute();                               // tile s
      __syncthreads();                         // LDS reads done
      stageB((s + 1) * 64);
      const int nd = (s + 2 < nsteps ? s + 2 : nsteps - 1) * 8;
      float zu, zv;
      loadx(nd, zu, zv);                       // x(s+2), rides with stage drain
      U4 e2 = expand_pack(yu), e3 = expand_pack(yv);
      *reinterpret_cast<U4*>(AA + aoff0) = e2;
      *reinterpret_cast<U4*>(AA + aoff1) = e3;
      yu = zu; yv = zv;
      __syncthreads();                         // tile s+1 visible
    }
    compute();                                 // tile nsteps-1
  }

  // ---- epilogue: Out = ns*acc (+ nb on z==0) ----
#pragma unroll
  for (int j = 0; j < 4; ++j) {
    int col   = n0 + w * 64 + j * 16 + l15;
    float nsv = nscale[col];
    float nbv = (BIAS && blockIdx.z == 0) ? nbias[col] : 0.0f;
#pragma unroll
    for (int i = 0; i < 4; ++i) {
      int rb = m0 + i * 16 + hi * 4;
#pragma unroll
      for (int r = 0; r < 4; ++r)
        outz[(size_t)(rb + r) * N + col] = (TOUT)(nsv * acc[i][j][r] + nbv);
    }
  }
}

// ---------------------------------------------------------------------------
// sum of 4 f16 partials + node_bias2 + residual -> LN(256) -> exact GELU
// ---------------------------------------------------------------------------
__global__ __launch_bounds__(256)
void ln_gelu_kernel(const f16* __restrict__ P, size_t zstride,
                    const float* __restrict__ X,  const float* __restrict__ nb2,
                    const float* __restrict__ gamma, const float* __restrict__ beta,
                    float* __restrict__ out, int rows) {
  int row  = blockIdx.x * 4 + (threadIdx.x >> 6);
  int lane = threadIdx.x & 63;
  if (row >= rows) return;
  const size_t base = (size_t)row * 256 + lane * 4;
  const float4 xr = *reinterpret_cast<const float4*>(X + base);
  const float4 nb = *reinterpret_cast<const float4*>(nb2 + lane * 4);
  const float4 g  = *reinterpret_cast<const float4*>(gamma + lane * 4);
  const float4 be = *reinterpret_cast<const float4*>(beta + lane * 4);
  float h[4] = { (&nb.x)[0] + (&xr.x)[0], (&nb.x)[1] + (&xr.x)[1],
                 (&nb.x)[2] + (&xr.x)[2], (&nb.x)[3] + (&xr.x)[3] };
#pragma unroll
  for (int z = 0; z < 4; ++z) {
    const half4 p4 = *reinterpret_cast<const half4*>(P + z * zstride + base);
#pragma unroll
    for (int j = 0; j < 4; ++j) h[j] += (float)p4[j];
  }
  float s = h[0] + h[1] + h[2] + h[3];
#pragma unroll
  for (int o = 32; o >= 1; o >>= 1) s += __shfl_xor(s, o);
  float mu = s * (1.0f / 256.0f);
  float vs = 0.f;
#pragma unroll
  for (int j = 0; j < 4; ++j) { float d = h[j] - mu; vs += d * d; }
#pragma unroll
  for (int o = 32; o >= 1; o >>= 1) vs += __shfl_xor(vs, o);
  float inv = rsqrtf(vs * (1.0f / 256.0f) + 1e-5f);
  float o4[4];
#pragma unroll
  for (int j = 0; j < 4; ++j) {
    float v = (h[j] - mu) * inv * (&g.x)[j] + (&be.x)[j];
    o4[j] = 0.5f * v * (1.0f + erff(v * 0.70710678118654752f));
  }
  *reinterpret_cast<float4*>(out + (size_t)row * 256 + lane * 4) =
      make_float4(o4[0], o4[1], o4[2], o4[3]);
}

// ---------------------------------------------------------------------------
extern "C" void kernel_launch(void* const* d_in, const int* in_sizes, int n_in,
                              void* d_out, int out_size, void* d_ws, size_t ws_size,
                              hipStream_t stream) {
  (void)in_sizes; (void)n_in; (void)out_size; (void)ws_size;
  const float* x     = (const float*)d_in[0];
  const float* coef1 = (const float*)d_in[2];
  const float* sb1   = (const float*)d_in[3];
  const float* ssp1  = (const float*)d_in[4];
  const float* ns1   = (const float*)d_in[5];
  const float* nb1   = (const float*)d_in[6];
  const float* coef2 = (const float*)d_in[8];
  const float* sb2   = (const float*)d_in[9];
  const float* ssp2  = (const float*)d_in[10];
  const float* ns2   = (const float*)d_in[11];
  const float* nb2   = (const float*)d_in[12];
  const float* lgam  = (const float*)d_in[13];
  const float* lbet  = (const float*)d_in[14];
  float* out = (float*)d_out;

  const int Ntok = 16 * 1024;
  const int D0 = 256, D1 = 512, D2 = 256;

  // ws: h1 partials 2 x [Ntok,512] f16 (33.6MB) | part 4 x [Ntok,256] f16
  //     (33.6MB) | Wt1 2.1MB | Wt2 2.1MB
  char* ws     = (char*)d_ws;
  f16*  h1p    = (f16*)ws;
  size_t h1z   = (size_t)Ntok * D1;            // elems per z-partial
  size_t off   = 2 * h1z * sizeof(f16);
  f16*  part   = (f16*)(ws + off);
  size_t partz = (size_t)Ntok * D2;
  off += 4 * partz * sizeof(f16);
  f16* Wt1 = (f16*)(ws + off);
  off += (size_t)D1 * D0 * 8 * sizeof(f16);
  f16* Wt2 = (f16*)(ws + off);

  prep_w_kernel<<<(D0 * D1 + 255) / 256, 256, 0, stream>>>(coef1, ssp1, sb1, Wt1, D0, D1);
  prep_w_kernel<<<(D1 * D2 + 255) / 256, 256, 0, stream>>>(coef2, ssp2, sb2, Wt2, D1, D2);

  // layer 1: split-K=2 -> 1024 blocks (3/CU). Partials: z0 = ns*acc+nb, z1 = ns*acc.
  kan_gemm<true, 1, float, f16><<<dim3(D1 / 256, Ntok / 64, 2), 256, 0, stream>>>(
      x, nullptr, D0, Wt1, D0 * 8, ns1, nb1, D1, h1p, D0 / 16);

  // layer 2: A = h1p0 + h1p1 (summed in staging); split-K=4 -> 1024 blocks.
  kan_gemm<false, 2, f16, f16><<<dim3(D2 / 256, Ntok / 64, 4), 256, 0, stream>>>(
      h1p, h1p + h1z, D1, Wt2, D1 * 8, ns2, nullptr, D2, part, D1 / 32);

  // reduce 4 partials + bias + residual + LN + GELU
  ln_gelu_kernel<<<Ntok / 4, 256, 0, stream>>>(
      part, partz, x, nb2, lgam, lbet, out, Ntok);
}

// Round 19
// 116.297 us; speedup vs baseline: 1.3343x; 1.1270x over previous
//
#include <hip/hip_runtime.h>
#include <cstdint>
#include <cstddef>

using f16   = _Float16;
using half4 = __attribute__((ext_vector_type(4))) _Float16;
using half8 = __attribute__((ext_vector_type(8))) _Float16;
using f32x4 = __attribute__((ext_vector_type(4))) float;
using ull   = unsigned long long;

#define DINL __device__ __forceinline__

// global -> LDS async, 16B per lane. LDS dest wave-uniform base + lane*16.
DINL void gload_lds16(const void* gptr, void* lptr) {
  __builtin_amdgcn_global_load_lds(
      reinterpret_cast<const __attribute__((address_space(1))) uint32_t*>(
          reinterpret_cast<uintptr_t>(gptr)),
      reinterpret_cast<__attribute__((address_space(3))) uint32_t*>(
          reinterpret_cast<uintptr_t>(lptr)),
      16, 0, 0);
}

DINL unsigned pkh(float a, float b) {
  unsigned short ha = __builtin_bit_cast(unsigned short, (f16)a);
  unsigned short hb = __builtin_bit_cast(unsigned short, (f16)b);
  return (unsigned)ha | ((unsigned)hb << 16);
}

struct U4 { unsigned x, y, z, w; };

// x -> 16B A-row: [B0..B5 uniform cubic B-spline, silu(x), 0] as 8 f16.
// Funnel-shift placement; validated rounds 5-17 (absmax 0.03125).
DINL U4 expand_pack(float x) {
  float xs = (x + 3.0f) * 1.5f;
  float mf = floorf(xs);
  int   m  = (int)mf;
  float u = xs - mf, u2 = u * u, u3 = u2 * u, um = 1.0f - u;
  float p3 = u3 * (1.0f / 6.0f);
  float p2 = (1.0f + 3.0f * (u + u2 - u3)) * (1.0f / 6.0f);
  float p1 = (4.0f - 6.0f * u2 + 3.0f * u3) * (1.0f / 6.0f);
  float p0 = um * um * um * (1.0f / 6.0f);
  ull P = (ull)pkh(p0, p1) | ((ull)pkh(p2, p3) << 32);
  if ((unsigned)m > 8u) P = 0;
  int s    = m * 16 - 48;
  int sneg = min(63, max(0, -s));
  int spos = min(63, max(0, s));
  int shi2 = min(63, max(0, s - 64));
  ull rlo = (s < 0) ? (P >> sneg) : ((s < 64) ? (P << spos) : 0ull);
  ull rhi = (s < 0) ? 0ull
                    : ((s < 64) ? ((P >> (63 - spos)) >> 1) : (P << shi2));
  float sil = x / (1.0f + __expf(-x));
  U4 r;
  r.x = (unsigned)rlo;
  r.y = (unsigned)(rlo >> 32);
  r.z = (unsigned)rhi;
  r.w = pkh(sil, 0.0f);
  return r;
}

// Merged weight prep for BOTH layers (one dispatch), PRE-SWIZZLED (rule 21):
// dim slot stored at (d&7)^(n&7) so linear global_load_lds yields the
// swizzled LDS tile. Per-element code identical to rounds 2-17.
__global__ __launch_bounds__(256)
void prep_w2_kernel(const float* __restrict__ coef1, const float* __restrict__ ssp1,
                    const float* __restrict__ sb1,   f16* __restrict__ Wt1, int n1,
                    const float* __restrict__ coef2, const float* __restrict__ ssp2,
                    const float* __restrict__ sb2,   f16* __restrict__ Wt2,
                    int Din1, int Dout1, int Din2, int Dout2) {
  int idx = blockIdx.x * 256 + threadIdx.x;
  const float *coef, *ssp, *sb;
  f16* Wt;
  int Din, Dout;
  if (idx < n1) {
    coef = coef1; ssp = ssp1; sb = sb1; Wt = Wt1; Din = Din1; Dout = Dout1;
  } else {
    idx -= n1;
    if (idx >= Din2 * Dout2) return;
    coef = coef2; ssp = ssp2; sb = sb2; Wt = Wt2; Din = Din2; Dout = Dout2;
  }
  int n = idx / Din;
  int d = idx - n * Din;
  float s = ssp[(size_t)d * Dout + n];
  const float* c = coef + ((size_t)d * Dout + n) * 6;
  half8 wv;
#pragma unroll
  for (int b = 0; b < 6; ++b) wv[b] = (f16)(c[b] * s);
  wv[6] = (f16)sb[(size_t)d * Dout + n];
  wv[7] = (f16)0.0f;
  int dp = (d & ~7) | ((d & 7) ^ (n & 7));
  *reinterpret_cast<half8*>(Wt + ((size_t)n * Din + dp) * 8) = wv;
}

// ---------------------------------------------------------------------------
// Fused KAN GEMM v11 (best measured: 118.6us total, absmax 0.03125):
// BM=64 x BN=256, 8 waves (2x4, 32x64/wave), BK=64, static 80KB LDS dbuf,
// 1 barrier/step, K-loop unrolled x2 with static buffer names + peeled tail.
// T5 setprio around MFMA cluster; f16 h1/partials (templated dtypes).
// ---------------------------------------------------------------------------
template <bool BIAS, typename TIN, typename TOUT>
__global__ __launch_bounds__(512, 4)
void kan_gemm(const TIN* __restrict__ X, int ldx,
              const f16* __restrict__ Wt, int ldw,
              const float* __restrict__ nscale, const float* __restrict__ nbias,
              int N, TOUT* __restrict__ Out, int nsteps) {
  __shared__ alignas(16) f16 A0[64 * 64];      //  8 KB
  __shared__ alignas(16) f16 A1[64 * 64];      //  8 KB
  __shared__ alignas(16) f16 B0[256 * 64];     // 32 KB
  __shared__ alignas(16) f16 B1[256 * 64];     // 32 KB

  const int tid  = threadIdx.x;
  const int w    = tid >> 6;
  const int lane = tid & 63;
  const int l15  = lane & 15, l7 = lane & 7, hi = lane >> 4;
  const int wm   = w >> 2, wn = w & 3;         // wave grid 2 x 4
  const int m0   = blockIdx.y * 64;
  const int n0   = blockIdx.x * 256;
  const int dim0 = blockIdx.z * (nsteps * 8);  // split-K dim offset
  TOUT* outz = Out + (size_t)blockIdx.z * ((size_t)gridDim.y * 64) * N;

  // A: 1 element/thread/step (64 rows x 8 dims = 512); asrc is DIM-indexed.
  const int ar = tid >> 3, ad = tid & 7;
  const TIN* asrc = X + (size_t)(m0 + ar) * ldx + dim0 + ad;
  const int aoff = ar * 64 + 8 * (ad ^ (ar & 7));

  // B: 4 x 16B chunks/thread (256 rows x 8 slots = 2048 chunks)
  const f16* wb[4];
  int ldsb[4];
#pragma unroll
  for (int q = 0; q < 4; ++q) {
    int c   = tid + q * 512;
    wb[q]   = Wt + (size_t)(n0 + (c >> 3)) * ldw + (size_t)dim0 * 8 + (c & 7) * 8;
    ldsb[q] = c * 8;
  }

  f32x4 acc[2][4] = {};

  auto stageB = [&](f16* buf, int k0) {
#pragma unroll
    for (int q = 0; q < 4; ++q) gload_lds16(wb[q] + k0, buf + ldsb[q]);
  };

  auto compute = [&](const f16* bA, const f16* bB) {
    __builtin_amdgcn_s_setprio(1);             // T5: favor MFMA-issuing wave
#pragma unroll
    for (int kk = 0; kk < 2; ++kk) {
      const int sl = kk * 4 + hi;
      half8 av[2], bv[4];
#pragma unroll
      for (int i = 0; i < 2; ++i)
        av[i] = *reinterpret_cast<const half8*>(
            bA + (wm * 32 + i * 16 + l15) * 64 + 8 * (sl ^ l7));
#pragma unroll
      for (int j = 0; j < 4; ++j)
        bv[j] = *reinterpret_cast<const half8*>(
            bB + (wn * 64 + j * 16 + l15) * 64 + 8 * (sl ^ l7));
#pragma unroll
      for (int i = 0; i < 2; ++i)
#pragma unroll
        for (int j = 0; j < 4; ++j)
          acc[i][j] = __builtin_amdgcn_mfma_f32_16x16x32_f16(av[i], bv[j], acc[i][j], 0, 0, 0);
    }
    __builtin_amdgcn_s_setprio(0);
  };

  auto writeA = [&](f16* buf, U4 e) {
    *reinterpret_cast<U4*>(buf + aoff) = e;
  };

  // ---- prologue: tile 0 in A0/B0; xn = x(1) in flight ----
  {
    float xa = (float)asrc[0];
    stageB(B0, 0);
    writeA(A0, expand_pack(xa));
  }
  float xn = (float)asrc[8];
  __syncthreads();

  // ---- steady state: 2 tiles per iteration, static buffers ----
  const TIN* ap = asrc + 16;                   // x(s+2) position (dim units)
  const int npairs = (nsteps - 2) >> 1;
  int k = 64;                                  // staging k0 for tile s+1
  for (int p = 0; p < npairs; ++p) {
    // half A: compute tile s (A0/B0); stage B(s+1)->B1; expand x(s+1)->A1
    stageB(B1, k);
    float xa2 = (float)ap[0];                  // x(s+2), issued early
    compute(A0, B0);
    writeA(A1, expand_pack(xn));
    __syncthreads();
    // half B: compute tile s+1 (A1/B1); stage B(s+2)->B0; expand x(s+2)->A0
    stageB(B0, k + 64);
    xn = (float)ap[8];                         // x(s+3), issued early
    compute(A1, B1);
    writeA(A0, expand_pack(xa2));
    __syncthreads();
    ap += 16;
    k  += 128;
  }

  // ---- tail: tiles nsteps-2 (A0/B0) and nsteps-1 (A1/B1) ----
  stageB(B1, k);                               // k == (nsteps-1)*64
  compute(A0, B0);
  writeA(A1, expand_pack(xn));
  __syncthreads();
  compute(A1, B1);

  // ---- epilogue: Out = ns*acc (+ nb) ----
#pragma unroll
  for (int j = 0; j < 4; ++j) {
    int col   = n0 + wn * 64 + j * 16 + l15;
    float nsv = nscale[col];
    float nbv = BIAS ? nbias[col] : 0.0f;
#pragma unroll
    for (int i = 0; i < 2; ++i) {
      int rb = m0 + wm * 32 + i * 16 + hi * 4;
#pragma unroll
      for (int r = 0; r < 4; ++r)
        outz[(size_t)(rb + r) * N + col] = (TOUT)(nsv * acc[i][j][r] + nbv);
    }
  }
}

// ---------------------------------------------------------------------------
// f16 partial0 + f16 partial1 + node_bias2 + residual -> LN(256) -> exact GELU
// ---------------------------------------------------------------------------
__global__ __launch_bounds__(256)
void ln_gelu_kernel(const f16* __restrict__ P0, const f16* __restrict__ P1,
                    const float* __restrict__ X,  const float* __restrict__ nb2,
                    const float* __restrict__ gamma, const float* __restrict__ beta,
                    float* __restrict__ out, int rows) {
  int row  = blockIdx.x * 4 + (threadIdx.x >> 6);
  int lane = threadIdx.x & 63;
  if (row >= rows) return;
  const half4  a4 = *reinterpret_cast<const half4*>(P0 + (size_t)row * 256 + lane * 4);
  const half4  b4 = *reinterpret_cast<const half4*>(P1 + (size_t)row * 256 + lane * 4);
  const float4 xr = *reinterpret_cast<const float4*>(X  + (size_t)row * 256 + lane * 4);
  const float4 nb = *reinterpret_cast<const float4*>(nb2 + lane * 4);
  const float4 g  = *reinterpret_cast<const float4*>(gamma + lane * 4);
  const float4 be = *reinterpret_cast<const float4*>(beta + lane * 4);
  float h[4];
#pragma unroll
  for (int j = 0; j < 4; ++j)
    h[j] = (float)a4[j] + (float)b4[j] + (&nb.x)[j] + (&xr.x)[j];
  float s = h[0] + h[1] + h[2] + h[3];
#pragma unroll
  for (int o = 32; o >= 1; o >>= 1) s += __shfl_xor(s, o);
  float mu = s * (1.0f / 256.0f);
  float vs = 0.f;
#pragma unroll
  for (int j = 0; j < 4; ++j) { float d = h[j] - mu; vs += d * d; }
#pragma unroll
  for (int o = 32; o >= 1; o >>= 1) vs += __shfl_xor(vs, o);
  float inv = rsqrtf(vs * (1.0f / 256.0f) + 1e-5f);
  float o4[4];
#pragma unroll
  for (int j = 0; j < 4; ++j) {
    float v = (h[j] - mu) * inv * (&g.x)[j] + (&be.x)[j];
    o4[j] = 0.5f * v * (1.0f + erff(v * 0.70710678118654752f));
  }
  *reinterpret_cast<float4*>(out + (size_t)row * 256 + lane * 4) =
      make_float4(o4[0], o4[1], o4[2], o4[3]);
}

// ---------------------------------------------------------------------------
extern "C" void kernel_launch(void* const* d_in, const int* in_sizes, int n_in,
                              void* d_out, int out_size, void* d_ws, size_t ws_size,
                              hipStream_t stream) {
  (void)in_sizes; (void)n_in; (void)out_size; (void)ws_size;
  const float* x     = (const float*)d_in[0];
  const float* coef1 = (const float*)d_in[2];
  const float* sb1   = (const float*)d_in[3];
  const float* ssp1  = (const float*)d_in[4];
  const float* ns1   = (const float*)d_in[5];
  const float* nb1   = (const float*)d_in[6];
  const float* coef2 = (const float*)d_in[8];
  const float* sb2   = (const float*)d_in[9];
  const float* ssp2  = (const float*)d_in[10];
  const float* ns2   = (const float*)d_in[11];
  const float* nb2   = (const float*)d_in[12];
  const float* lgam  = (const float*)d_in[13];
  const float* lbet  = (const float*)d_in[14];
  float* out = (float*)d_out;

  const int Ntok = 16 * 1024;
  const int D0 = 256, D1 = 512, D2 = 256;

  // ws: h1 [Ntok,512] f16 (16.8MB) | part [2][Ntok,256] f16 (16.8MB) | Wt1 | Wt2
  char* ws    = (char*)d_ws;
  f16*  h1    = (f16*)ws;
  size_t off  = (size_t)Ntok * D1 * sizeof(f16);
  f16*  part  = (f16*)(ws + off);
  off += (size_t)2 * Ntok * D2 * sizeof(f16);
  f16* Wt1 = (f16*)(ws + off);
  off += (size_t)D1 * D0 * 8 * sizeof(f16);
  f16* Wt2 = (f16*)(ws + off);

  // merged weight prep: one dispatch covers both layers
  const int n1 = D0 * D1, n2 = D1 * D2;
  prep_w2_kernel<<<(n1 + n2 + 255) / 256, 256, 0, stream>>>(
      coef1, ssp1, sb1, Wt1, n1, coef2, ssp2, sb2, Wt2, D0, D1, D1, D2);

  // layer 1: [16384 x 2048] x [512 x 2048]^T -> h1 (f16). 512 blocks, 2/CU.
  kan_gemm<true, float, f16><<<dim3(D1 / 256, Ntok / 64, 1), 512, 0, stream>>>(
      x, D0, Wt1, D0 * 8, ns1, nb1, D1, h1, D0 / 8);

  // layer 2: full-width N=256, split-K=2 -> 512 blocks; f16 partials ns2*acc.
  kan_gemm<false, f16, f16><<<dim3(D2 / 256, Ntok / 64, 2), 512, 0, stream>>>(
      h1, D1, Wt2, D1 * 8, ns2, nullptr, D2, part, D1 / 16);

  // reduce partials + bias + residual + LN + GELU
  ln_gelu_kernel<<<Ntok / 4, 256, 0, stream>>>(
      part, part + (size_t)Ntok * D2, x, nb2, lgam, lbet, out, Ntok);
}